// Round 7
// baseline (261.809 us; speedup 1.0000x reference)
//
#include <hip/hip_runtime.h>

// InstantNGP hash-grid forward, fp32 — corner-per-lane layout (R6) plus an
// A/B test of L1-bypass gathers (sc0) via the official buffer-load builtins
// (compiler-tracked; the two inline-asm attempts at this corrupted state).
//
// 8 lanes per (point, level), one corner per lane; dx = lane bit 0 so dx
// pairs coalesce to one 64B line on linear levels; duplicate slots at l>=12
// (z-stride wrapped to 0; l15 y-stride 2^19 vanishes under &mask) hit the
// same-address broadcast path. 8-lane shfl_xor butterfly reduces corners.
//
// Level constants (verified vs reference _level_consts(), HW-validated R4/R6):
//   res = 16<<l ; mask = (1<<min(12+3l,19))-1
//   l 0-2  : linear, strides [1, res, res^2]
//   l 3-11 : hash (primes 1, 2654435761, 805459861)
//   l 12-15: linear, strides [1, res, 0]
//
// Model (R1/R2/R6 fit): dur ≈ lines/pt × ~3.0 cy/line per CU, independent of
// residency -> suspect per-CU L1 lookup/miss path. MODE 1 issues gathers with
// sc0 (SE scope: skip L1, serve from XCD L2) to test that theory.

static constexpr int N_PTS = 500000;

typedef float f4 __attribute__((ext_vector_type(4)));

template<int MODE>
__global__ __launch_bounds__(256) void hashgrid_fwd(
    const float* __restrict__ coords,   // [N,3]
    const float* __restrict__ table,    // [T,4]
    float* __restrict__ out,            // [N,64]
    int pbase,                          // first point of this launch
    unsigned tbytes)                    // table bytes (buffer NumRecords)
{
    const unsigned tid = threadIdx.x;
    const unsigned p = tid >> 7;          // local point (0..1)
    const unsigned l = (tid >> 3) & 15u;  // level
    const unsigned c = tid & 7u;          // corner
    const unsigned dx = c & 1u;
    const unsigned dy = (c >> 1) & 1u;
    const unsigned dz = c >> 2;

    const unsigned n = (unsigned)pbase + blockIdx.x * 2u + p;

    const float cx = coords[(size_t)n * 3u + 0u];
    const float cy = coords[(size_t)n * 3u + 1u];
    const float cz = coords[(size_t)n * 3u + 2u];

    const unsigned res = 16u << l;
    const float scale = (float)(res - 1u);

    // pos = c*scale + 0.5, no fma contraction (match np fp32 floor boundaries)
    const float px = __fadd_rn(__fmul_rn(cx, scale), 0.5f);
    const float py = __fadd_rn(__fmul_rn(cy, scale), 0.5f);
    const float pz = __fadd_rn(__fmul_rn(cz, scale), 0.5f);
    const float bxf = floorf(px), byf = floorf(py), bzf = floorf(pz);
    const float fx = __fsub_rn(px, bxf);
    const float fy = __fsub_rn(py, byf);
    const float fz = __fsub_rn(pz, bzf);
    const unsigned x = (unsigned)(int)bxf + dx;
    const unsigned y = (unsigned)(int)byf + dy;
    const unsigned z = (unsigned)(int)bzf + dz;

    const unsigned mask = (l >= 3u) ? 0x7FFFFu : ((1u << (12u + 3u * l)) - 1u);

    // this lane's trilinear weight, product order matches np.prod (x*y*z)
    const float wx = dx ? fx : (1.0f - fx);
    const float wy = dy ? fy : (1.0f - fy);
    const float wz = dz ? fz : (1.0f - fz);
    const float w = wx * wy * wz;

    unsigned slot;
    if (l >= 3u && l < 12u) {           // hash levels
        slot = (x ^ (y * 2654435761u) ^ (z * 805459861u)) & mask;
    } else {                            // linear levels
        const unsigned zs = (l < 3u) ? res * res : 0u;   // l>=12: z-stride 0
        slot = (x + y * res + z * zs) & mask;            // uint32 wrap = ref
    }

    f4 e;
    if constexpr (MODE == 1) {
#if __has_builtin(__builtin_amdgcn_make_buffer_rsrc) && \
    __has_builtin(__builtin_amdgcn_raw_buffer_load_b128)
        // raw buffer load, aux=1 -> sc0 (SE scope): bypass L1, serve from L2
        auto rsrc = __builtin_amdgcn_make_buffer_rsrc(
            (void*)table, (short)0, (int)tbytes, 0x00020000);
        auto r = __builtin_amdgcn_raw_buffer_load_b128(
            rsrc, (int)(slot * 16u), 0, 1);
        e = __builtin_bit_cast(f4, r);
#else
        e = *(const f4*)(table + (size_t)slot * 4u);
#endif
    } else {
        e = *(const f4*)(table + (size_t)slot * 4u);
    }

    float r0 = w * e.x;
    float r1 = w * e.y;
    float r2 = w * e.z;
    float r3 = w * e.w;

    // butterfly reduce over the 8 corner lanes
    #pragma unroll
    for (int m = 1; m <= 4; m <<= 1) {
        r0 += __shfl_xor(r0, m, 64);
        r1 += __shfl_xor(r1, m, 64);
        r2 += __shfl_xor(r2, m, 64);
        r3 += __shfl_xor(r3, m, 64);
    }

    if (c == 0u) {
        f4 o; o.x = r0; o.y = r1; o.z = r2; o.w = r3;
        __builtin_nontemporal_store(o, (f4*)(out + (size_t)n * 64u + (size_t)l * 4u));
    }
}

extern "C" void kernel_launch(void* const* d_in, const int* in_sizes, int n_in,
                              void* d_out, int out_size, void* d_ws, size_t ws_size,
                              hipStream_t stream) {
    const float* coords = (const float*)d_in[0];
    const float* table  = (const float*)d_in[1];
    float* out = (float*)d_out;
    const unsigned tbytes = (unsigned)in_sizes[1] * 4u;

    const int half = N_PTS / 2;        // 250000 points per dispatch
    const int blocks = half / 2;       // 2 points per 256-thread block
    hipLaunchKernelGGL(hashgrid_fwd<0>, dim3(blocks), dim3(256), 0, stream,
                       coords, table, out, 0, tbytes);
    hipLaunchKernelGGL(hashgrid_fwd<1>, dim3(blocks), dim3(256), 0, stream,
                       coords, table, out, half, tbytes);
}